// Round 12
// baseline (220.114 us; speedup 1.0000x reference)
//
#include <hip/hip_runtime.h>
#include <math.h>

#define NG 300
#define NP 100000
#define NC 80
#define PRED_COLS 85   // 5 + NC
#define ALPHA_C 0.75f
#define BETA_C  1.0f
#define EPS_C   1e-7f
#define TPB 256
#define NBLK ((NP + TPB - 1) / TPB)   // 391 pred blocks
#define KCAP 10
#define NSLAB 20              // gt slabs for cost kernel
#define GSLAB (NG / NSLAB)    // 15

__device__ __forceinline__ float fast_rcp(float x) {
    return __builtin_amdgcn_rcpf(x);
}

__device__ __forceinline__ float wave_min(float v) {
#pragma unroll
    for (int off = 32; off >= 1; off >>= 1)
        v = fminf(v, __shfl_xor(v, off));
    return v;
}

// lexicographic (val, idx) wave-min butterfly; all 64 lanes converge.
__device__ __forceinline__ void wave_lexmin(float& v, int& i) {
#pragma unroll
    for (int off = 32; off >= 1; off >>= 1) {
        float ov = __shfl_xor(v, off);
        int   oi = __shfl_xor(i, off);
        if (ov < v || (ov == v && oi < i)) { v = ov; i = oi; }
    }
}

// ---------------------------------------------------------------------------
// Kernel P: prep.  FULL=true: y==0 packs box-derived float4s + classes 0..39;
// y==1 does classes 40..79 and (block 0) the per-gt derived values gtm/gtc.
// FULL=false: gt-derived values only (no preds-side outputs touched).
// BUGFIX vs R11: gt init uses a strided loop (NG=300 > TPB=256; the old
// `threadIdx.x < NG` guard left gtm/gtc[256..299] as 0xAA poison -> the
// cost kernel indexed probs ~2.8e9 floats OOB -> HSA memory fault).
// ---------------------------------------------------------------------------
template <bool FULL>
__global__ __launch_bounds__(TPB) void prep_kernel(
    const float* __restrict__ preds, float* __restrict__ probs,
    float4* __restrict__ bA, float4* __restrict__ bB,
    const float* __restrict__ gt_boxes, const int* __restrict__ gt_classes,
    float4* __restrict__ gtm, int* __restrict__ gtc)
{
    if (blockIdx.y == 1 && blockIdx.x == 0) {
        for (int g = threadIdx.x; g < NG; g += TPB) {
            float4 b = ((const float4*)gt_boxes)[g];
            float x1 = b.x, y1 = b.y, x2 = b.z, y2 = b.w;
            float4 m;
            m.x = fmaxf(x2 - x1, 0.f) * fmaxf(y2 - y1, 0.f);
            m.y = (x1 + x2) * 0.5f;
            m.z = (y1 + y2) * 0.5f;
            m.w = atanf(fmaxf(x2 - x1, EPS_C) / fmaxf(y2 - y1, EPS_C));
            gtm[g] = m;
            gtc[g] = gt_classes[g] * NP;
        }
    }
    if (!FULL) return;
    int p = blockIdx.x * TPB + threadIdx.x;
    if (p >= NP) return;
    const float* row = preds + (size_t)p * PRED_COLS;
    if (blockIdx.y == 0) {
        float xc = row[0], yc = row[1], w = row[2], h = row[3];
        float px1 = xc - w * 0.5f, py1 = yc - h * 0.5f;
        float px2 = xc + w * 0.5f, py2 = yc + h * 0.5f;
        float4 a = {px1, py1, px2, py2};
        float4 b;
        b.x = fmaxf(px2 - px1, 0.f) * fmaxf(py2 - py1, 0.f);
        b.y = (px1 + px2) * 0.5f;
        b.z = (py1 + py2) * 0.5f;
        b.w = atanf(fmaxf(px2 - px1, EPS_C) / fmaxf(py2 - py1, EPS_C));
        bA[p] = a; bB[p] = b;
#pragma unroll
        for (int c = 0; c < 40; ++c)
            probs[(size_t)c * NP + p] = fast_rcp(1.f + expf(-row[5 + c]));
    } else {
#pragma unroll
        for (int c = 40; c < 80; ++c)
            probs[(size_t)c * NP + p] = fast_rcp(1.f + expf(-row[5 + c]));
    }
}

// ---------------------------------------------------------------------------
// Kernel A: cost matrix, scalar (1 pred/thread -- R10's VEC=4 regressed:
// VALU time identical, TLP halved).  grid = (391, NSLAB).  gt data read via
// wave-UNIFORM global loads (s_load from K$) -- no LDS in the hot loop, no
// barrier before it.  Probs preloaded to registers; inner loop: pure VALU +
// one coalesced store.  Byproduct: per-(gt, block) min -> mins[g][391].
// ---------------------------------------------------------------------------
template <bool USE_PACK>
__global__ __launch_bounds__(TPB) void cost_kernel(
    const float* __restrict__ preds, const float* __restrict__ gt_boxes,
    const int* __restrict__ gt_classes, float* __restrict__ cost,
    const float* __restrict__ probs,
    const float4* __restrict__ bA, const float4* __restrict__ bB,
    const float4* __restrict__ gtm, const int* __restrict__ gtc,
    float* __restrict__ mins)
{
    __shared__ float swmin[4][GSLAB];   // only for the final cross-wave min

    const int g0 = blockIdx.y * GSLAB;
    const int lane = threadIdx.x & 63;
    const int wid  = threadIdx.x >> 6;

    const int p = blockIdx.x * TPB + threadIdx.x;
    const bool valid = p < NP;
    const int pc = valid ? p : NP - 1;   // clamp: loads safe, results masked

    float px1, py1, px2, py2, areap, pcx, pcy, atp;
    const float* row = preds + (size_t)pc * PRED_COLS;
    if (USE_PACK) {
        float4 a = bA[pc], b = bB[pc];
        px1 = a.x; py1 = a.y; px2 = a.z; py2 = a.w;
        areap = b.x; pcx = b.y; pcy = b.z; atp = b.w;
    } else {
        float xc = row[0], yc = row[1], w = row[2], h = row[3];
        px1 = xc - w * 0.5f; py1 = yc - h * 0.5f;
        px2 = xc + w * 0.5f; py2 = yc + h * 0.5f;
        areap = fmaxf(px2 - px1, 0.f) * fmaxf(py2 - py1, 0.f);
        pcx = (px1 + px2) * 0.5f; pcy = (py1 + py2) * 0.5f;
        atp = atanf(fmaxf(px2 - px1, EPS_C) / fmaxf(py2 - py1, EPS_C));
    }

    // preload the 15 per-gt probs (gtc read is uniform -> scalar load)
    float prob[GSLAB];
#pragma unroll
    for (int i = 0; i < GSLAB; ++i) {
        if (USE_PACK) prob[i] = probs[(size_t)gtc[g0 + i] + pc];
        else          prob[i] = fast_rcp(1.f + expf(-row[5 + gt_classes[g0 + i]]));
    }

    const float VC = (float)(4.0 / (M_PI * M_PI));
    const float4* gtb4 = (const float4*)gt_boxes;
    float* out = cost + (size_t)g0 * NP + p;
    float mn[GSLAB];

#pragma unroll 5
    for (int i = 0; i < GSLAB; ++i) {
        float4 b = gtb4[g0 + i];   // uniform -> s_load (K$), frees LDS/VALU
        float4 m = gtm[g0 + i];    // uniform -> s_load
        float gx1 = b.x, gy1 = b.y, gx2 = b.z, gy2 = b.w;
        float xx1 = fmaxf(px1, gx1), yy1 = fmaxf(py1, gy1);
        float xx2 = fminf(px2, gx2), yy2 = fminf(py2, gy2);
        float inter = fmaxf(xx2 - xx1, 0.f) * fmaxf(yy2 - yy1, 0.f);
        float uni = areap + m.x - inter + EPS_C;
        float iou = inter * fast_rcp(uni);
        float dx = pcx - m.y, dy = pcy - m.z;
        float cd2 = dx * dx + dy * dy;
        float cw = fmaxf(fmaxf(px2, gx2) - fminf(px1, gx1), EPS_C);
        float ch = fmaxf(fmaxf(py2, gy2) - fminf(py1, gy1), EPS_C);
        float c2 = cw * cw + ch * ch + EPS_C;
        float dat = m.w - atp;
        float v = VC * dat * dat;
        float alpha_t = v * fast_rcp(1.f - iou + v + EPS_C);
        float ciou = iou - cd2 * fast_rcp(c2) - alpha_t * v;

        float cst = ALPHA_C * (1.f - prob[i]) +
                    BETA_C * (1.f - fminf(fmaxf(ciou, 0.f), 1.f));
        mn[i] = valid ? cst : INFINITY;
        if (valid) out[(size_t)i * NP] = cst;
    }

    // per-gt block-min: wave butterfly + cross-wave LDS combine
#pragma unroll
    for (int i = 0; i < GSLAB; ++i) {
        float v = wave_min(mn[i]);
        if (lane == 0) swmin[wid][i] = v;
    }
    __syncthreads();
    if (threadIdx.x < GSLAB) {
        int t = threadIdx.x;
        float v = fminf(fminf(swmin[0][t], swmin[1][t]),
                        fminf(swmin[2][t], swmin[3][t]));
        mins[(size_t)(g0 + t) * NBLK + blockIdx.x] = v;
    }
}

// ---------------------------------------------------------------------------
// Kernel B (fused, R9-proven): per gt -- thr = 10th-smallest block-min
// (wave-0 knockout over 391); gather qualifying blocks (min <= thr, ties
// included, no cap); scan only those (~10 x 256 elements vs 100K) with the
// exact ballot+shfl insertion machinery (order-independent); wave-0 merge;
// Kt from epoch schedule; write assignments.
// Pruning proof: the 10 smallest block-mins are 10 distinct real elements
// <= thr, so any x > thr has >=10 strict lex predecessors; and x in top-10
// => value(x) <= thr => its block min <= thr => block gathered.
// ---------------------------------------------------------------------------
__global__ __launch_bounds__(TPB) void topk_fused(
    const float* __restrict__ cost, const float* __restrict__ mins,
    const int* __restrict__ epoch, const int* __restrict__ total_epochs,
    float* __restrict__ out_assign)
{
    const int g = blockIdx.x;
    const int lane = threadIdx.x & 63;
    const int wid  = threadIdx.x >> 6;

    __shared__ float s_thr;
    __shared__ int   s_qn;
    __shared__ int   qlist[NBLK];
    __shared__ float swv[4 * KCAP];
    __shared__ int   swi[4 * KCAP];

    if (threadIdx.x == 0) s_qn = 0;
    __syncthreads();

    const float* mrow = mins + (size_t)g * NBLK;

    // wave 0: thr = 10th-smallest of 391 block-mins (knockout)
    if (wid == 0) {
        float v[7];
#pragma unroll
        for (int j = 0; j < 7; ++j) {
            int idx = lane + j * 64;
            v[j] = (idx < NBLK) ? mrow[idx] : INFINITY;
        }
        float last = INFINITY;
        for (int k = 0; k < KCAP; ++k) {
            float lm = v[0];
#pragma unroll
            for (int j = 1; j < 7; ++j) lm = fminf(lm, v[j]);
            float wv = lm; int wi = lane;
            wave_lexmin(wv, wi);
            last = wv;
            if (lane == wi) {
                bool done = false;
#pragma unroll
                for (int j = 0; j < 7; ++j)
                    if (!done && v[j] == lm) { v[j] = INFINITY; done = true; }
            }
        }
        if (lane == 0) s_thr = last;
    }
    __syncthreads();
    const float thr0 = s_thr;

    // gather qualifying blocks (order-independent downstream, atomics fine)
    for (int b = threadIdx.x; b < NBLK; b += TPB)
        if (mrow[b] <= thr0) qlist[atomicAdd(&s_qn, 1)] = b;
    __syncthreads();
    const int qn = s_qn;

    float thr = thr0;
    float ev = INFINITY; int ei = 0x7fffffff;
    const float* crow = cost + (size_t)g * NP;

    for (int qi = wid; qi < qn; qi += 4) {
        const int b = qlist[qi];
        const int ib = b * TPB + lane * 4;
        float vq[4];
        if (b == NBLK - 1) {
#pragma unroll
            for (int q = 0; q < 4; ++q)
                vq[q] = (ib + q < NP) ? crow[ib + q] : INFINITY;
        } else {
            float4 v = *(const float4*)(crow + ib);
            vq[0] = v.x; vq[1] = v.y; vq[2] = v.z; vq[3] = v.w;
        }
#pragma unroll
        for (int q = 0; q < 4; ++q) {
            unsigned long long m = __ballot(vq[q] <= thr);
            while (m) {
                int l = __ffsll(m) - 1;
                m &= m - 1;
                float cv = __shfl(vq[q], l);
                int   ci = __shfl(ib, l) + q;
                if (!(cv <= thr)) continue;   // thr may have tightened
                bool prec = (ev < cv) || (ev == cv && ei < ci);
                unsigned long long bb = __ballot(prec) & 0x3FFull;
                int pos = __popcll(bb);
                if (pos < KCAP) {
                    float pev = __shfl_up(ev, 1);
                    int   pei = __shfl_up(ei, 1);
                    if (lane > pos && lane < KCAP) { ev = pev; ei = pei; }
                    if (lane == pos)               { ev = cv;  ei = ci;  }
                    thr = fminf(thr, __shfl(ev, KCAP - 1));
                }
            }
        }
    }

    if (lane < KCAP) { swv[wid * KCAP + lane] = ev; swi[wid * KCAP + lane] = ei; }
    __syncthreads();

    if (wid == 0) {
        float mv = (lane < 4 * KCAP) ? swv[lane] : INFINITY;
        int   mi = (lane < 4 * KCAP) ? swi[lane] : 0x7fffffff;

        int ep = epoch[0], te = total_epochs[0];
        int denom = te - 1; if (denom < 1) denom = 1;
        double tt = (double)ep / (double)denom;
        int K = (int)rint(10.0 - 9.0 * tt);
        if (K < 1) K = 1; if (K > 10) K = 10;
        int Kt = (K < NP) ? K : NP;

        for (int k = 0; k < Kt; ++k) {
            float wv = mv; int wi = mi;
            wave_lexmin(wv, wi);
            if (lane == 0) {
                out_assign[2 * ((size_t)g * Kt + k) + 0] = (float)wi;
                out_assign[2 * ((size_t)g * Kt + k) + 1] = (float)g;
            }
            if (mv == wv && mi == wi) { mv = INFINITY; mi = 0x7fffffff; }
        }
    }
}

// ---------------------------------------------------------------------------
extern "C" void kernel_launch(void* const* d_in, const int* in_sizes, int n_in,
                              void* d_out, int out_size, void* d_ws, size_t ws_size,
                              hipStream_t stream)
{
    const float* preds        = (const float*)d_in[0];
    const float* gt_boxes     = (const float*)d_in[1];
    const int*   gt_classes   = (const int*)d_in[2];
    const int*   epoch        = (const int*)d_in[3];
    const int*   total_epochs = (const int*)d_in[4];

    float* cost       = (float*)d_out;
    float* out_assign = cost + (size_t)NG * NP;

    size_t probBytes = (size_t)NC * NP * sizeof(float);   // 32 MB
    size_t packBytes = (size_t)NP * 8 * sizeof(float);    // 3.2 MB
    size_t gtmBytes  = (size_t)NG * 4 * sizeof(float);    // 4.8 KB
    size_t gtcBytes  = (size_t)NG * sizeof(int) + 848;    // pad to 16B align
    size_t minsBytes = (size_t)NG * NBLK * sizeof(float); // ~459 KB

    char* wsp = (char*)d_ws;
    bool usePack = ws_size >= probBytes + packBytes + gtmBytes + gtcBytes + minsBytes;

    float *probs, *minsb; float4 *bA, *bB, *gtm; int *gtc;
    if (usePack) {
        probs = (float*)wsp;
        bA    = (float4*)(wsp + probBytes);
        bB    = (float4*)(wsp + probBytes + packBytes / 2);
        gtm   = (float4*)(wsp + probBytes + packBytes);
        gtc   = (int*)   (wsp + probBytes + packBytes + gtmBytes);
        minsb = (float*) (wsp + probBytes + packBytes + gtmBytes + gtcBytes);
    } else {
        probs = nullptr; bA = nullptr; bB = nullptr;
        gtm   = (float4*)wsp;
        gtc   = (int*)   (wsp + gtmBytes);
        minsb = (float*) (wsp + gtmBytes + gtcBytes);
    }

    if (usePack) {
        prep_kernel<true ><<<dim3(NBLK, 2), TPB, 0, stream>>>(
            preds, probs, bA, bB, gt_boxes, gt_classes, gtm, gtc);
        cost_kernel<true ><<<dim3(NBLK, NSLAB), TPB, 0, stream>>>(
            preds, gt_boxes, gt_classes, cost, probs, bA, bB, gtm, gtc, minsb);
    } else {
        prep_kernel<false><<<dim3(1, 2), TPB, 0, stream>>>(
            preds, probs, bA, bB, gt_boxes, gt_classes, gtm, gtc);  // gt-derived only
        cost_kernel<false><<<dim3(NBLK, NSLAB), TPB, 0, stream>>>(
            preds, gt_boxes, gt_classes, cost, probs, bA, bB, gtm, gtc, minsb);
    }
    topk_fused<<<NG, TPB, 0, stream>>>(cost, minsb, epoch, total_epochs, out_assign);
}